// Round 2
// baseline (4384.491 us; speedup 1.0000x reference)
//
#include <hip/hip_runtime.h>
#include <math.h>

#define NB 32
#define LSEQ 2048
#define DIN 64
#define NH 256
#define NN 32
#define NLAY 2
#define NCH 16
#define TCH 128   // LSEQ/NCH
#define ML1 350
#define ML2 400
#define MOUT 1024
#define LN_EPS 1e-5f

// ---------------- coefficient prep ----------------
__global__ void s4w_coef(const float* __restrict__ log_dt,
                         const float* __restrict__ C_re, const float* __restrict__ C_im,
                         const float* __restrict__ log_A_real, const float* __restrict__ A_imag,
                         float* __restrict__ ctr, float* __restrict__ cti,
                         float* __restrict__ er_, float* __restrict__ ei_,
                         float* __restrict__ pr_, float* __restrict__ pi_) {
    int idx = blockIdx.x * 256 + threadIdx.x;
    if (idx >= NLAY * NH * NN) return;
    int h = (idx / NN) % NH;
    int l = idx / (NN * NH);
    float dt = expf(log_dt[l * NH + h]);
    float ar = -expf(log_A_real[idx]);
    float ai = A_imag[idx];
    float dre = ar * dt, dim = ai * dt;
    float ex = expf(dre);
    float er = ex * cosf(dim);
    float ei = ex * sinf(dim);
    float den = ar * ar + ai * ai;
    float qr = ((er - 1.0f) * ar + ei * ai) / den;
    float qi = (ei * ar - (er - 1.0f) * ai) / den;
    float cr = C_re[idx], ci = C_im[idx];
    ctr[idx] = 2.0f * (cr * qr - ci * qi);
    cti[idx] = 2.0f * (cr * qi + ci * qr);
    er_[idx] = er; ei_[idx] = ei;
    // E^TCH in double for angle accuracy (angle up to ~1250 rad)
    double exT = exp((double)dre * (double)TCH);
    double ang = (double)dim * (double)TCH;
    pr_[idx] = (float)(exT * cos(ang));
    pi_[idx] = (float)(exT * sin(ang));
}

// ---------------- encoder: h[b][l][o] = sum_i x[b,l,i] w[o,i] + bias[o] ----------------
__global__ void s4w_enc(const float* __restrict__ x, const float* __restrict__ w,
                        const float* __restrict__ bias, float* __restrict__ hbuf) {
    int gid = blockIdx.x * 256 + threadIdx.x;       // (b,l) flat
    int b = gid / LSEQ, li = gid % LSEQ;
    int o0 = blockIdx.y * 64;
    float xr[DIN];
    const float4* xp = (const float4*)(x + (size_t)(b * LSEQ + li) * DIN);
#pragma unroll
    for (int i = 0; i < DIN / 4; i++) {
        float4 v = xp[i];
        xr[4 * i] = v.x; xr[4 * i + 1] = v.y; xr[4 * i + 2] = v.z; xr[4 * i + 3] = v.w;
    }
    float* hp = hbuf + ((size_t)b * LSEQ + li) * NH + o0;
    for (int og = 0; og < 16; og++) {
        float a4[4];
#pragma unroll
        for (int q = 0; q < 4; q++) {
            int o = o0 + og * 4 + q;
            float acc = bias[o];
            const float* wp = w + o * DIN;
#pragma unroll
            for (int i = 0; i < DIN; i++) acc = fmaf(wp[i], xr[i], acc);
            a4[q] = acc;
        }
        ((float4*)hp)[og] = make_float4(a4[0], a4[1], a4[2], a4[3]);
    }
}

// ---------------- conv phase A: per-chunk local end states ----------------
// block = (b, c), thread = h. Reads u[b][l][h]: 1 KB contiguous per step.
__global__ void s4w_convA(const float* __restrict__ hbuf,
                          const float* __restrict__ er_, const float* __restrict__ ei_,
                          float2* __restrict__ states, int layer) {
    int b = blockIdx.x, c = blockIdx.y, h = threadIdx.x;
    float er[NN], ei[NN], sr[NN], si[NN];
    const float* eb0 = er_ + (size_t)(layer * NH + h) * NN;
    const float* eb1 = ei_ + (size_t)(layer * NH + h) * NN;
#pragma unroll
    for (int n = 0; n < NN; n++) { er[n] = eb0[n]; ei[n] = eb1[n]; sr[n] = 0.f; si[n] = 0.f; }
    const float* up = hbuf + ((size_t)b * LSEQ + c * TCH) * NH + h;
#pragma unroll 4
    for (int j = 0; j < TCH; j++) {
        float u = up[(size_t)j * NH];
#pragma unroll
        for (int n = 0; n < NN; n++) {
            float nsr = fmaf(er[n], sr[n], fmaf(-ei[n], si[n], u));
            float nsi = fmaf(er[n], si[n], ei[n] * sr[n]);
            sr[n] = nsr; si[n] = nsi;
        }
    }
    float2* sp = states + ((size_t)(b * NCH + c) * NH + h) * NN;
#pragma unroll
    for (int n = 0; n < NN; n++) sp[n] = make_float2(sr[n], si[n]);
}

// ---------------- conv phase B: inter-chunk scan (in place: end -> start states) ----------------
__global__ void s4w_scan(float2* __restrict__ states,
                         const float* __restrict__ pr_, const float* __restrict__ pi_, int layer) {
    int idx = blockIdx.x * 256 + threadIdx.x;  // b * (NH*NN)
    int b = idx / (NH * NN);
    int hn = idx % (NH * NN);
    float pr = pr_[(size_t)layer * NH * NN + hn];
    float pi = pi_[(size_t)layer * NH * NN + hn];
    float sr = 0.f, si = 0.f;
    float2* sp = states + (size_t)b * NCH * NH * NN + hn;
    for (int c = 0; c < NCH; c++) {
        float2 e = sp[(size_t)c * NH * NN];
        sp[(size_t)c * NH * NN] = make_float2(sr, si);
        float nsr = pr * sr - pi * si + e.x;
        float nsi = pr * si + pi * sr + e.y;
        sr = nsr; si = nsi;
    }
}

// ---------------- conv phase C: replay + Dp skip + exact GELU ----------------
__global__ void s4w_convC(const float* __restrict__ hbuf, float* __restrict__ ybuf,
                          const float2* __restrict__ states,
                          const float* __restrict__ er_, const float* __restrict__ ei_,
                          const float* __restrict__ ctr_, const float* __restrict__ cti_,
                          const float* __restrict__ Dp, int layer) {
    int b = blockIdx.x, c = blockIdx.y, h = threadIdx.x;
    float er[NN], ei[NN], sr[NN], si[NN], cr[NN], ci[NN];
    size_t cbase = (size_t)(layer * NH + h) * NN;
    const float2* sp = states + ((size_t)(b * NCH + c) * NH + h) * NN;
#pragma unroll
    for (int n = 0; n < NN; n++) {
        er[n] = er_[cbase + n]; ei[n] = ei_[cbase + n];
        cr[n] = ctr_[cbase + n]; ci[n] = cti_[cbase + n];
        float2 s0 = sp[n];
        sr[n] = s0.x; si[n] = s0.y;
    }
    float dp = Dp[layer * NH + h];
    const float* up = hbuf + ((size_t)b * LSEQ + c * TCH) * NH + h;
    float* yp = ybuf + ((size_t)b * LSEQ + c * TCH) * NH + h;
#pragma unroll 2
    for (int j = 0; j < TCH; j++) {
        float u = up[(size_t)j * NH];
        float a0 = 0.f, a1 = 0.f;
#pragma unroll
        for (int n = 0; n < NN; n++) {
            float nsr = fmaf(er[n], sr[n], fmaf(-ei[n], si[n], u));
            float nsi = fmaf(er[n], si[n], ei[n] * sr[n]);
            sr[n] = nsr; si[n] = nsi;
            if (n & 1) { a1 = fmaf(cr[n], nsr, a1); a1 = fmaf(-ci[n], nsi, a1); }
            else       { a0 = fmaf(cr[n], nsr, a0); a0 = fmaf(-ci[n], nsi, a0); }
        }
        float yv = a0 + a1;
        yv = fmaf(u, dp, yv);
        float g = 0.5f * yv * (1.0f + erff(yv * 0.70710678118f));
        yp[(size_t)j * NH] = g;
    }
}

// ---------------- transpose out_w to K-major: wT[k][o] ----------------
__global__ void s4w_trow(const float* __restrict__ ow, float* __restrict__ owT, int layer) {
    int idx = blockIdx.x * 256 + threadIdx.x;   // 512*256
    int o = idx / NH, k = idx % NH;
    owT[(size_t)k * 2 * NH + o] = ow[(size_t)layer * 2 * NH * NH + (size_t)o * NH + k];
}

// ---------------- proj GEMM + GLU + residual + channel-LN (in-place h update) ----------------
// block = (b, 16-wide l tile); thread t owns out-channels (t, t+256) for 16 l's.
__global__ void s4w_proj(const float* __restrict__ ybuf, float* __restrict__ hbuf,
                         const float* __restrict__ owT, const float* __restrict__ ob,
                         const float* __restrict__ lnw, const float* __restrict__ lnb, int layer) {
    int b = blockIdx.x / (LSEQ / 16);
    int l0 = (blockIdx.x % (LSEQ / 16)) * 16;
    int t = threadIdx.x;
    __shared__ __align__(16) float ys[NH][16];   // k-major: ys[k][l]
    __shared__ float ps[256], pq[256];
    __shared__ float mean_s[16], inv_s[16];

    // stage y tile transposed to k-major; global reads 64 B contiguous per thread
    {
        int l = t & 15;
        int k0 = (t >> 4) * 16;
        const float4* yp = (const float4*)(ybuf + ((size_t)b * LSEQ + l0 + l) * NH + k0);
#pragma unroll
        for (int q = 0; q < 4; q++) {
            float4 v = yp[q];
            ys[k0 + 4 * q + 0][l] = v.x;
            ys[k0 + 4 * q + 1][l] = v.y;
            ys[k0 + 4 * q + 2][l] = v.z;
            ys[k0 + 4 * q + 3][l] = v.w;
        }
    }
    __syncthreads();

    float acca[16], accg[16];
#pragma unroll
    for (int i = 0; i < 16; i++) { acca[i] = 0.f; accg[i] = 0.f; }

#pragma unroll 4
    for (int k = 0; k < NH; k++) {
        float wa = owT[(size_t)k * 2 * NH + t];
        float wg = owT[(size_t)k * 2 * NH + NH + t];
        const float4* yr = (const float4*)&ys[k][0];
        float4 y0 = yr[0], y1 = yr[1], y2 = yr[2], y3 = yr[3];
        float yv[16] = { y0.x, y0.y, y0.z, y0.w, y1.x, y1.y, y1.z, y1.w,
                         y2.x, y2.y, y2.z, y2.w, y3.x, y3.y, y3.z, y3.w };
#pragma unroll
        for (int lc = 0; lc < 16; lc++) {
            acca[lc] = fmaf(wa, yv[lc], acca[lc]);
            accg[lc] = fmaf(wg, yv[lc], accg[lc]);
        }
    }

    // epilogue: bias + GLU + residual (residual reads coalesced per-l)
    float ob0 = ob[layer * 2 * NH + t];
    float ob1 = ob[layer * 2 * NH + NH + t];
    float r[16];
#pragma unroll
    for (int lc = 0; lc < 16; lc++) {
        float hres = hbuf[((size_t)b * LSEQ + l0 + lc) * NH + t];
        float a = acca[lc] + ob0;
        float g = accg[lc] + ob1;
        float v = a * (1.0f / (1.0f + expf(-g)));
        r[lc] = v + hres;
    }

    // channel LayerNorm over t (H=256) for each of the 16 columns
    __syncthreads();                     // all k-loop reads of ys done
#pragma unroll
    for (int lc = 0; lc < 16; lc++) ys[t][lc] = r[lc];
    __syncthreads();
    {
        int col = t & 15, rp = t >> 4;
        float s = 0.f, q = 0.f;
#pragma unroll
        for (int i = 0; i < 16; i++) {
            float v = ys[rp * 16 + i][col];
            s += v; q = fmaf(v, v, q);
        }
        ps[t] = s; pq[t] = q;
    }
    __syncthreads();
    if (t < 16) {
        float S = 0.f, Q = 0.f;
#pragma unroll
        for (int i = 0; i < 16; i++) { S += ps[t + 16 * i]; Q += pq[t + 16 * i]; }
        float m = S / (float)NH;
        float v = Q / (float)NH - m * m;
        mean_s[t] = m;
        inv_s[t] = rsqrtf(v + LN_EPS);
    }
    __syncthreads();
    float lw = lnw[layer * NH + t], lb = lnb[layer * NH + t];
#pragma unroll
    for (int lc = 0; lc < 16; lc++) {
        float outv = (r[lc] - mean_s[lc]) * inv_s[lc] * lw + lb;
        hbuf[((size_t)b * LSEQ + l0 + lc) * NH + t] = outv;
    }
}

// ---------------- gather last timestep ----------------
__global__ void s4w_gather(const float* __restrict__ hbuf, float* __restrict__ hl) {
    int idx = blockIdx.x * 256 + threadIdx.x;   // b*NH
    int b = idx / NH, t = idx % NH;
    hl[idx] = hbuf[((size_t)b * LSEQ + (LSEQ - 1)) * NH + t];
}

// ---------------- small MLP layer ----------------
__global__ void s4w_mlp(const float* __restrict__ in, const float* __restrict__ w,
                        const float* __restrict__ bias, float* __restrict__ out,
                        int K, int N, int do_relu) {
    int idx = blockIdx.x * 256 + threadIdx.x;
    if (idx >= NB * N) return;
    int b = idx / N, o = idx % N;
    const float* ip = in + (size_t)b * K;
    const float* wp = w + (size_t)o * K;
    float acc = bias[o];
    for (int k = 0; k < K; k++) acc = fmaf(ip[k], wp[k], acc);
    if (do_relu) acc = fmaxf(acc, 0.f);
    out[idx] = acc;
}

extern "C" void kernel_launch(void* const* d_in, const int* in_sizes, int n_in,
                              void* d_out, int out_size, void* d_ws, size_t ws_size,
                              hipStream_t stream) {
    const float* x          = (const float*)d_in[0];
    const float* enc_w      = (const float*)d_in[1];
    const float* enc_b      = (const float*)d_in[2];
    const float* log_dt     = (const float*)d_in[3];
    const float* C_re       = (const float*)d_in[4];
    const float* C_im       = (const float*)d_in[5];
    const float* log_A_real = (const float*)d_in[6];
    const float* A_imag     = (const float*)d_in[7];
    const float* Dp         = (const float*)d_in[8];
    const float* out_w      = (const float*)d_in[9];
    const float* out_b      = (const float*)d_in[10];
    const float* ln_w       = (const float*)d_in[11];
    const float* ln_b       = (const float*)d_in[12];
    const float* lin1_w     = (const float*)d_in[13];
    const float* lin1_b     = (const float*)d_in[14];
    const float* lin2_w     = (const float*)d_in[15];
    const float* lin2_b     = (const float*)d_in[16];
    const float* lin3_w     = (const float*)d_in[17];
    const float* lin3_b     = (const float*)d_in[18];
    float* outp = (float*)d_out;

    float* ws = (float*)d_ws;
    size_t off = 0;
    float* hbuf   = ws + off; off += (size_t)NB * LSEQ * NH;           // 16.78M
    float* ybuf   = ws + off; off += (size_t)NB * LSEQ * NH;           // 16.78M
    float2* states = (float2*)(ws + off); off += (size_t)NB * NCH * NH * NN * 2; // 8.39M floats
    float* ctr    = ws + off; off += NLAY * NH * NN;
    float* cti    = ws + off; off += NLAY * NH * NN;
    float* er_    = ws + off; off += NLAY * NH * NN;
    float* ei_    = ws + off; off += NLAY * NH * NN;
    float* pr_    = ws + off; off += NLAY * NH * NN;
    float* pi_    = ws + off; off += NLAY * NH * NN;
    float* owT    = ws + off; off += 2 * NH * NH;
    float* hl     = ws + off; off += NB * NH;
    float* t1     = ws + off; off += NB * ML1;
    float* t2     = ws + off; off += NB * ML2;

    s4w_coef<<<(NLAY * NH * NN + 255) / 256, 256, 0, stream>>>(
        log_dt, C_re, C_im, log_A_real, A_imag, ctr, cti, er_, ei_, pr_, pi_);

    s4w_enc<<<dim3(NB * LSEQ / 256, 4), 256, 0, stream>>>(x, enc_w, enc_b, hbuf);

    for (int layer = 0; layer < NLAY; layer++) {
        s4w_convA<<<dim3(NB, NCH), 256, 0, stream>>>(hbuf, er_, ei_, states, layer);
        s4w_scan<<<(NB * NH * NN) / 256, 256, 0, stream>>>(states, pr_, pi_, layer);
        s4w_convC<<<dim3(NB, NCH), 256, 0, stream>>>(hbuf, ybuf, states, er_, ei_, ctr, cti, Dp, layer);
        s4w_trow<<<(2 * NH * NH) / 256, 256, 0, stream>>>(out_w, owT, layer);
        s4w_proj<<<NB * (LSEQ / 16), 256, 0, stream>>>(ybuf, hbuf, owT, out_b, ln_w, ln_b, layer);
    }

    s4w_gather<<<(NB * NH) / 256, 256, 0, stream>>>(hbuf, hl);
    s4w_mlp<<<(NB * ML1 + 255) / 256, 256, 0, stream>>>(hl, lin1_w, lin1_b, t1, NH, ML1, 1);
    s4w_mlp<<<(NB * ML2 + 255) / 256, 256, 0, stream>>>(t1, lin2_w, lin2_b, t2, ML1, ML2, 1);
    s4w_mlp<<<(NB * MOUT + 255) / 256, 256, 0, stream>>>(t2, lin3_w, lin3_b, outp, ML2, MOUT, 0);
}

// Round 3
// 1052.784 us; speedup vs baseline: 4.1647x; 4.1647x over previous
//
#include <hip/hip_runtime.h>
#include <math.h>

#define NB 32
#define LSEQ 2048
#define DIN 64
#define NH 256
#define NN 32
#define NLAY 2
#define NCH 16
#define TCH 128   // LSEQ/NCH
#define ML1 350
#define ML2 400
#define MOUT 1024
#define LN_EPS 1e-5f

// ---------------- coefficient prep ----------------
__global__ void s4w_coef(const float* __restrict__ log_dt,
                         const float* __restrict__ C_re, const float* __restrict__ C_im,
                         const float* __restrict__ log_A_real, const float* __restrict__ A_imag,
                         float* __restrict__ ctr, float* __restrict__ cti,
                         float* __restrict__ er_, float* __restrict__ ei_,
                         float* __restrict__ pr_, float* __restrict__ pi_) {
    int idx = blockIdx.x * 256 + threadIdx.x;
    if (idx >= NLAY * NH * NN) return;
    int h = (idx / NN) % NH;
    int l = idx / (NN * NH);
    float dt = expf(log_dt[l * NH + h]);
    float ar = -expf(log_A_real[idx]);
    float ai = A_imag[idx];
    float dre = ar * dt, dim = ai * dt;
    float ex = expf(dre);
    float er = ex * cosf(dim);
    float ei = ex * sinf(dim);
    float den = ar * ar + ai * ai;
    float qr = ((er - 1.0f) * ar + ei * ai) / den;
    float qi = (ei * ar - (er - 1.0f) * ai) / den;
    float cr = C_re[idx], ci = C_im[idx];
    ctr[idx] = 2.0f * (cr * qr - ci * qi);
    cti[idx] = 2.0f * (cr * qi + ci * qr);
    er_[idx] = er; ei_[idx] = ei;
    // E^TCH in double for angle accuracy (angle up to ~1250 rad)
    double exT = exp((double)dre * (double)TCH);
    double ang = (double)dim * (double)TCH;
    pr_[idx] = (float)(exT * cos(ang));
    pi_[idx] = (float)(exT * sin(ang));
}

// ---------------- encoder: h[b][l][o] = sum_i x[b,l,i] w[o,i] + bias[o] ----------------
__global__ void __launch_bounds__(256, 1)
s4w_enc(const float* __restrict__ x, const float* __restrict__ w,
        const float* __restrict__ bias, float* __restrict__ hbuf) {
    int gid = blockIdx.x * 256 + threadIdx.x;       // (b,l) flat
    int b = gid / LSEQ, li = gid % LSEQ;
    int o0 = blockIdx.y * 64;
    float xr[DIN];
    const float4* xp = (const float4*)(x + (size_t)(b * LSEQ + li) * DIN);
#pragma unroll
    for (int i = 0; i < DIN / 4; i++) {
        float4 v = xp[i];
        xr[4 * i] = v.x; xr[4 * i + 1] = v.y; xr[4 * i + 2] = v.z; xr[4 * i + 3] = v.w;
    }
    float* hp = hbuf + ((size_t)b * LSEQ + li) * NH + o0;
    for (int og = 0; og < 16; og++) {
        float a4[4];
#pragma unroll
        for (int q = 0; q < 4; q++) {
            int o = o0 + og * 4 + q;
            float acc = bias[o];
            const float* wp = w + o * DIN;
#pragma unroll
            for (int i = 0; i < DIN; i++) acc = fmaf(wp[i], xr[i], acc);
            a4[q] = acc;
        }
        ((float4*)hp)[og] = make_float4(a4[0], a4[1], a4[2], a4[3]);
    }
}

// ---------------- conv phase A: per-chunk local end states ----------------
// block = (b, c), thread = h. Reads u[b][l][h]: 1 KB contiguous per step.
__global__ void __launch_bounds__(256, 1)
s4w_convA(const float* __restrict__ hbuf,
          const float* __restrict__ er_, const float* __restrict__ ei_,
          float2* __restrict__ states, int layer) {
    int b = blockIdx.x, c = blockIdx.y, h = threadIdx.x;
    float er[NN], ei[NN], sr[NN], si[NN];
    const float* eb0 = er_ + (size_t)(layer * NH + h) * NN;
    const float* eb1 = ei_ + (size_t)(layer * NH + h) * NN;
#pragma unroll
    for (int n = 0; n < NN; n++) { er[n] = eb0[n]; ei[n] = eb1[n]; sr[n] = 0.f; si[n] = 0.f; }
    const float* up = hbuf + ((size_t)b * LSEQ + c * TCH) * NH + h;
#pragma unroll 4
    for (int j = 0; j < TCH; j++) {
        float u = up[(size_t)j * NH];
#pragma unroll
        for (int n = 0; n < NN; n++) {
            float nsr = fmaf(er[n], sr[n], fmaf(-ei[n], si[n], u));
            float nsi = fmaf(er[n], si[n], ei[n] * sr[n]);
            sr[n] = nsr; si[n] = nsi;
        }
    }
    float2* sp = states + ((size_t)(b * NCH + c) * NH + h) * NN;
#pragma unroll
    for (int n = 0; n < NN; n++) sp[n] = make_float2(sr[n], si[n]);
}

// ---------------- conv phase B: inter-chunk scan (in place: end -> start states) ----------------
__global__ void s4w_scan(float2* __restrict__ states,
                         const float* __restrict__ pr_, const float* __restrict__ pi_, int layer) {
    int idx = blockIdx.x * 256 + threadIdx.x;  // b * (NH*NN)
    int b = idx / (NH * NN);
    int hn = idx % (NH * NN);
    float pr = pr_[(size_t)layer * NH * NN + hn];
    float pi = pi_[(size_t)layer * NH * NN + hn];
    float sr = 0.f, si = 0.f;
    float2* sp = states + (size_t)b * NCH * NH * NN + hn;
    for (int c = 0; c < NCH; c++) {
        float2 e = sp[(size_t)c * NH * NN];
        sp[(size_t)c * NH * NN] = make_float2(sr, si);
        float nsr = pr * sr - pi * si + e.x;
        float nsi = pr * si + pi * sr + e.y;
        sr = nsr; si = nsi;
    }
}

// ---------------- conv phase C: replay + Dp skip + exact GELU ----------------
__global__ void __launch_bounds__(256, 1)
s4w_convC(const float* __restrict__ hbuf, float* __restrict__ ybuf,
          const float2* __restrict__ states,
          const float* __restrict__ er_, const float* __restrict__ ei_,
          const float* __restrict__ ctr_, const float* __restrict__ cti_,
          const float* __restrict__ Dp, int layer) {
    int b = blockIdx.x, c = blockIdx.y, h = threadIdx.x;
    float er[NN], ei[NN], sr[NN], si[NN], cr[NN], ci[NN];
    size_t cbase = (size_t)(layer * NH + h) * NN;
    const float2* sp = states + ((size_t)(b * NCH + c) * NH + h) * NN;
#pragma unroll
    for (int n = 0; n < NN; n++) {
        er[n] = er_[cbase + n]; ei[n] = ei_[cbase + n];
        cr[n] = ctr_[cbase + n]; ci[n] = cti_[cbase + n];
        float2 s0 = sp[n];
        sr[n] = s0.x; si[n] = s0.y;
    }
    float dp = Dp[layer * NH + h];
    const float* up = hbuf + ((size_t)b * LSEQ + c * TCH) * NH + h;
    float* yp = ybuf + ((size_t)b * LSEQ + c * TCH) * NH + h;
#pragma unroll 2
    for (int j = 0; j < TCH; j++) {
        float u = up[(size_t)j * NH];
        float a0 = 0.f, a1 = 0.f;
#pragma unroll
        for (int n = 0; n < NN; n++) {
            float nsr = fmaf(er[n], sr[n], fmaf(-ei[n], si[n], u));
            float nsi = fmaf(er[n], si[n], ei[n] * sr[n]);
            sr[n] = nsr; si[n] = nsi;
            if (n & 1) { a1 = fmaf(cr[n], nsr, a1); a1 = fmaf(-ci[n], nsi, a1); }
            else       { a0 = fmaf(cr[n], nsr, a0); a0 = fmaf(-ci[n], nsi, a0); }
        }
        float yv = a0 + a1;
        yv = fmaf(u, dp, yv);
        float g = 0.5f * yv * (1.0f + erff(yv * 0.70710678118f));
        yp[(size_t)j * NH] = g;
    }
}

// ---------------- transpose out_w to K-major: wT[k][o] ----------------
__global__ void s4w_trow(const float* __restrict__ ow, float* __restrict__ owT, int layer) {
    int idx = blockIdx.x * 256 + threadIdx.x;   // 512*256
    int o = idx / NH, k = idx % NH;
    owT[(size_t)k * 2 * NH + o] = ow[(size_t)layer * 2 * NH * NH + (size_t)o * NH + k];
}

// ---------------- proj GEMM + GLU + residual + channel-LN (in-place h update) ----------------
// block = (b, 16-wide l tile); thread t owns out-channels (t, t+256) for 16 l's.
__global__ void __launch_bounds__(256, 2)
s4w_proj(const float* __restrict__ ybuf, float* __restrict__ hbuf,
         const float* __restrict__ owT, const float* __restrict__ ob,
         const float* __restrict__ lnw, const float* __restrict__ lnb, int layer) {
    int b = blockIdx.x / (LSEQ / 16);
    int l0 = (blockIdx.x % (LSEQ / 16)) * 16;
    int t = threadIdx.x;
    __shared__ __align__(16) float ys[NH][16];   // k-major: ys[k][l]
    __shared__ float ps[256], pq[256];
    __shared__ float mean_s[16], inv_s[16];

    // stage y tile transposed to k-major; global reads 64 B contiguous per thread
    {
        int l = t & 15;
        int k0 = (t >> 4) * 16;
        const float4* yp = (const float4*)(ybuf + ((size_t)b * LSEQ + l0 + l) * NH + k0);
#pragma unroll
        for (int q = 0; q < 4; q++) {
            float4 v = yp[q];
            ys[k0 + 4 * q + 0][l] = v.x;
            ys[k0 + 4 * q + 1][l] = v.y;
            ys[k0 + 4 * q + 2][l] = v.z;
            ys[k0 + 4 * q + 3][l] = v.w;
        }
    }
    __syncthreads();

    float acca[16], accg[16];
#pragma unroll
    for (int i = 0; i < 16; i++) { acca[i] = 0.f; accg[i] = 0.f; }

#pragma unroll 4
    for (int k = 0; k < NH; k++) {
        float wa = owT[(size_t)k * 2 * NH + t];
        float wg = owT[(size_t)k * 2 * NH + NH + t];
        const float4* yr = (const float4*)&ys[k][0];
        float4 y0 = yr[0], y1 = yr[1], y2 = yr[2], y3 = yr[3];
        float yv[16] = { y0.x, y0.y, y0.z, y0.w, y1.x, y1.y, y1.z, y1.w,
                         y2.x, y2.y, y2.z, y2.w, y3.x, y3.y, y3.z, y3.w };
#pragma unroll
        for (int lc = 0; lc < 16; lc++) {
            acca[lc] = fmaf(wa, yv[lc], acca[lc]);
            accg[lc] = fmaf(wg, yv[lc], accg[lc]);
        }
    }

    // epilogue: bias + GLU + residual (residual reads coalesced per-l)
    float ob0 = ob[layer * 2 * NH + t];
    float ob1 = ob[layer * 2 * NH + NH + t];
    float r[16];
#pragma unroll
    for (int lc = 0; lc < 16; lc++) {
        float hres = hbuf[((size_t)b * LSEQ + l0 + lc) * NH + t];
        float a = acca[lc] + ob0;
        float g = accg[lc] + ob1;
        float v = a * (1.0f / (1.0f + expf(-g)));
        r[lc] = v + hres;
    }

    // channel LayerNorm over t (H=256) for each of the 16 columns
    __syncthreads();                     // all k-loop reads of ys done
#pragma unroll
    for (int lc = 0; lc < 16; lc++) ys[t][lc] = r[lc];
    __syncthreads();
    {
        int col = t & 15, rp = t >> 4;
        float s = 0.f, q = 0.f;
#pragma unroll
        for (int i = 0; i < 16; i++) {
            float v = ys[rp * 16 + i][col];
            s += v; q = fmaf(v, v, q);
        }
        ps[t] = s; pq[t] = q;
    }
    __syncthreads();
    if (t < 16) {
        float S = 0.f, Q = 0.f;
#pragma unroll
        for (int i = 0; i < 16; i++) { S += ps[t + 16 * i]; Q += pq[t + 16 * i]; }
        float m = S / (float)NH;
        float v = Q / (float)NH - m * m;
        mean_s[t] = m;
        inv_s[t] = rsqrtf(v + LN_EPS);
    }
    __syncthreads();
    float lw = lnw[layer * NH + t], lb = lnb[layer * NH + t];
#pragma unroll
    for (int lc = 0; lc < 16; lc++) {
        float outv = (r[lc] - mean_s[lc]) * inv_s[lc] * lw + lb;
        hbuf[((size_t)b * LSEQ + l0 + lc) * NH + t] = outv;
    }
}

// ---------------- gather last timestep ----------------
__global__ void s4w_gather(const float* __restrict__ hbuf, float* __restrict__ hl) {
    int idx = blockIdx.x * 256 + threadIdx.x;   // b*NH
    int b = idx / NH, t = idx % NH;
    hl[idx] = hbuf[((size_t)b * LSEQ + (LSEQ - 1)) * NH + t];
}

// ---------------- small MLP layer ----------------
__global__ void s4w_mlp(const float* __restrict__ in, const float* __restrict__ w,
                        const float* __restrict__ bias, float* __restrict__ out,
                        int K, int N, int do_relu) {
    int idx = blockIdx.x * 256 + threadIdx.x;
    if (idx >= NB * N) return;
    int b = idx / N, o = idx % N;
    const float* ip = in + (size_t)b * K;
    const float* wp = w + (size_t)o * K;
    float acc = bias[o];
    for (int k = 0; k < K; k++) acc = fmaf(ip[k], wp[k], acc);
    if (do_relu) acc = fmaxf(acc, 0.f);
    out[idx] = acc;
}

extern "C" void kernel_launch(void* const* d_in, const int* in_sizes, int n_in,
                              void* d_out, int out_size, void* d_ws, size_t ws_size,
                              hipStream_t stream) {
    const float* x          = (const float*)d_in[0];
    const float* enc_w      = (const float*)d_in[1];
    const float* enc_b      = (const float*)d_in[2];
    const float* log_dt     = (const float*)d_in[3];
    const float* C_re       = (const float*)d_in[4];
    const float* C_im       = (const float*)d_in[5];
    const float* log_A_real = (const float*)d_in[6];
    const float* A_imag     = (const float*)d_in[7];
    const float* Dp         = (const float*)d_in[8];
    const float* out_w      = (const float*)d_in[9];
    const float* out_b      = (const float*)d_in[10];
    const float* ln_w       = (const float*)d_in[11];
    const float* ln_b       = (const float*)d_in[12];
    const float* lin1_w     = (const float*)d_in[13];
    const float* lin1_b     = (const float*)d_in[14];
    const float* lin2_w     = (const float*)d_in[15];
    const float* lin2_b     = (const float*)d_in[16];
    const float* lin3_w     = (const float*)d_in[17];
    const float* lin3_b     = (const float*)d_in[18];
    float* outp = (float*)d_out;

    float* ws = (float*)d_ws;
    size_t off = 0;
    float* hbuf   = ws + off; off += (size_t)NB * LSEQ * NH;           // 16.78M
    float* ybuf   = ws + off; off += (size_t)NB * LSEQ * NH;           // 16.78M
    float2* states = (float2*)(ws + off); off += (size_t)NB * NCH * NH * NN * 2; // 8.39M floats
    float* ctr    = ws + off; off += NLAY * NH * NN;
    float* cti    = ws + off; off += NLAY * NH * NN;
    float* er_    = ws + off; off += NLAY * NH * NN;
    float* ei_    = ws + off; off += NLAY * NH * NN;
    float* pr_    = ws + off; off += NLAY * NH * NN;
    float* pi_    = ws + off; off += NLAY * NH * NN;
    float* owT    = ws + off; off += 2 * NH * NH;
    float* hl     = ws + off; off += NB * NH;
    float* t1     = ws + off; off += NB * ML1;
    float* t2     = ws + off; off += NB * ML2;

    s4w_coef<<<(NLAY * NH * NN + 255) / 256, 256, 0, stream>>>(
        log_dt, C_re, C_im, log_A_real, A_imag, ctr, cti, er_, ei_, pr_, pi_);

    s4w_enc<<<dim3(NB * LSEQ / 256, 4), 256, 0, stream>>>(x, enc_w, enc_b, hbuf);

    for (int layer = 0; layer < NLAY; layer++) {
        s4w_convA<<<dim3(NB, NCH), 256, 0, stream>>>(hbuf, er_, ei_, states, layer);
        s4w_scan<<<(NB * NH * NN) / 256, 256, 0, stream>>>(states, pr_, pi_, layer);
        s4w_convC<<<dim3(NB, NCH), 256, 0, stream>>>(hbuf, ybuf, states, er_, ei_, ctr, cti, Dp, layer);
        s4w_trow<<<(2 * NH * NH) / 256, 256, 0, stream>>>(out_w, owT, layer);
        s4w_proj<<<NB * (LSEQ / 16), 256, 0, stream>>>(ybuf, hbuf, owT, out_b, ln_w, ln_b, layer);
    }

    s4w_gather<<<(NB * NH) / 256, 256, 0, stream>>>(hbuf, hl);
    s4w_mlp<<<(NB * ML1 + 255) / 256, 256, 0, stream>>>(hl, lin1_w, lin1_b, t1, NH, ML1, 1);
    s4w_mlp<<<(NB * ML2 + 255) / 256, 256, 0, stream>>>(t1, lin2_w, lin2_b, t2, ML1, ML2, 1);
    s4w_mlp<<<(NB * MOUT + 255) / 256, 256, 0, stream>>>(t2, lin3_w, lin3_b, outp, ML2, MOUT, 0);
}

// Round 4
// 737.805 us; speedup vs baseline: 5.9426x; 1.4269x over previous
//
#include <hip/hip_runtime.h>
#include <hip/hip_bf16.h>
#include <math.h>

#define NB 32
#define LSEQ 2048
#define DIN 64
#define NH 256
#define NN 32
#define NLAY 2
#define NCH 16
#define TCH 128   // LSEQ/NCH
#define LTILE 64
#define ML1 350
#define ML2 400
#define MOUT 1024
#define LN_EPS 1e-5f

typedef short short8 __attribute__((ext_vector_type(8)));
typedef float f32x4 __attribute__((ext_vector_type(4)));

// ---------------- coefficient prep ----------------
__global__ void s4w_coef(const float* __restrict__ log_dt,
                         const float* __restrict__ C_re, const float* __restrict__ C_im,
                         const float* __restrict__ log_A_real, const float* __restrict__ A_imag,
                         float* __restrict__ ctr, float* __restrict__ cti,
                         float* __restrict__ er_, float* __restrict__ ei_,
                         float* __restrict__ pr_, float* __restrict__ pi_) {
    int idx = blockIdx.x * 256 + threadIdx.x;
    if (idx >= NLAY * NH * NN) return;
    int h = (idx / NN) % NH;
    int l = idx / (NN * NH);
    float dt = expf(log_dt[l * NH + h]);
    float ar = -expf(log_A_real[idx]);
    float ai = A_imag[idx];
    float dre = ar * dt, dim = ai * dt;
    float ex = expf(dre);
    float er = ex * cosf(dim);
    float ei = ex * sinf(dim);
    float den = ar * ar + ai * ai;
    float qr = ((er - 1.0f) * ar + ei * ai) / den;
    float qi = (ei * ar - (er - 1.0f) * ai) / den;
    float cr = C_re[idx], ci = C_im[idx];
    ctr[idx] = 2.0f * (cr * qr - ci * qi);
    cti[idx] = 2.0f * (cr * qi + ci * qr);
    er_[idx] = er; ei_[idx] = ei;
    double exT = exp((double)dre * (double)TCH);
    double ang = (double)dim * (double)TCH;
    pr_[idx] = (float)(exT * cos(ang));
    pi_[idx] = (float)(exT * sin(ang));
}

// ---------------- weight prep: out_w -> bf16 (both layers) ----------------
__global__ void s4w_wprep(const float* __restrict__ ow, __hip_bfloat16* __restrict__ wbf) {
    int idx = blockIdx.x * 256 + threadIdx.x;   // NLAY*512*256
    wbf[idx] = __float2bfloat16(ow[idx]);
}

// ---------------- encoder: h[b][l][o] ----------------
__global__ void __launch_bounds__(256, 1)
s4w_enc(const float* __restrict__ x, const float* __restrict__ w,
        const float* __restrict__ bias, float* __restrict__ hbuf) {
    int gid = blockIdx.x * 256 + threadIdx.x;
    int b = gid / LSEQ, li = gid % LSEQ;
    int o0 = blockIdx.y * 64;
    float xr[DIN];
    const float4* xp = (const float4*)(x + (size_t)(b * LSEQ + li) * DIN);
#pragma unroll
    for (int i = 0; i < DIN / 4; i++) {
        float4 v = xp[i];
        xr[4 * i] = v.x; xr[4 * i + 1] = v.y; xr[4 * i + 2] = v.z; xr[4 * i + 3] = v.w;
    }
    float* hp = hbuf + ((size_t)b * LSEQ + li) * NH + o0;
    for (int og = 0; og < 16; og++) {
        float a4[4];
#pragma unroll
        for (int q = 0; q < 4; q++) {
            int o = o0 + og * 4 + q;
            float acc = bias[o];
            const float* wp = w + o * DIN;
#pragma unroll
            for (int i = 0; i < DIN; i++) acc = fmaf(wp[i], xr[i], acc);
            a4[q] = acc;
        }
        ((float4*)hp)[og] = make_float4(a4[0], a4[1], a4[2], a4[3]);
    }
}

// ---------------- conv phase A ----------------
__global__ void __launch_bounds__(256, 1)
s4w_convA(const float* __restrict__ hbuf,
          const float* __restrict__ er_, const float* __restrict__ ei_,
          float2* __restrict__ states, int layer) {
    int b = blockIdx.x, c = blockIdx.y, h = threadIdx.x;
    float er[NN], ei[NN], sr[NN], si[NN];
    const float* eb0 = er_ + (size_t)(layer * NH + h) * NN;
    const float* eb1 = ei_ + (size_t)(layer * NH + h) * NN;
#pragma unroll
    for (int n = 0; n < NN; n++) { er[n] = eb0[n]; ei[n] = eb1[n]; sr[n] = 0.f; si[n] = 0.f; }
    const float* up = hbuf + ((size_t)b * LSEQ + c * TCH) * NH + h;
#pragma unroll 4
    for (int j = 0; j < TCH; j++) {
        float u = up[(size_t)j * NH];
#pragma unroll
        for (int n = 0; n < NN; n++) {
            float nsr = fmaf(er[n], sr[n], fmaf(-ei[n], si[n], u));
            float nsi = fmaf(er[n], si[n], ei[n] * sr[n]);
            sr[n] = nsr; si[n] = nsi;
        }
    }
    float2* sp = states + ((size_t)(b * NCH + c) * NH + h) * NN;
#pragma unroll
    for (int n = 0; n < NN; n++) sp[n] = make_float2(sr[n], si[n]);
}

// ---------------- conv phase B: inter-chunk scan ----------------
__global__ void s4w_scan(float2* __restrict__ states,
                         const float* __restrict__ pr_, const float* __restrict__ pi_, int layer) {
    int idx = blockIdx.x * 256 + threadIdx.x;
    int b = idx / (NH * NN);
    int hn = idx % (NH * NN);
    float pr = pr_[(size_t)layer * NH * NN + hn];
    float pi = pi_[(size_t)layer * NH * NN + hn];
    float sr = 0.f, si = 0.f;
    float2* sp = states + (size_t)b * NCH * NH * NN + hn;
    for (int c = 0; c < NCH; c++) {
        float2 e = sp[(size_t)c * NH * NN];
        sp[(size_t)c * NH * NN] = make_float2(sr, si);
        float nsr = pr * sr - pi * si + e.x;
        float nsi = pr * si + pi * sr + e.y;
        sr = nsr; si = nsi;
    }
}

// ---------------- conv phase C: replay + Dp skip + GELU -> bf16 ----------------
__global__ void __launch_bounds__(256, 1)
s4w_convC(const float* __restrict__ hbuf, __hip_bfloat16* __restrict__ ybf,
          const float2* __restrict__ states,
          const float* __restrict__ er_, const float* __restrict__ ei_,
          const float* __restrict__ ctr_, const float* __restrict__ cti_,
          const float* __restrict__ Dp, int layer) {
    int b = blockIdx.x, c = blockIdx.y, h = threadIdx.x;
    float er[NN], ei[NN], sr[NN], si[NN], cr[NN], ci[NN];
    size_t cbase = (size_t)(layer * NH + h) * NN;
    const float2* sp = states + ((size_t)(b * NCH + c) * NH + h) * NN;
#pragma unroll
    for (int n = 0; n < NN; n++) {
        er[n] = er_[cbase + n]; ei[n] = ei_[cbase + n];
        cr[n] = ctr_[cbase + n]; ci[n] = cti_[cbase + n];
        float2 s0 = sp[n];
        sr[n] = s0.x; si[n] = s0.y;
    }
    float dp = Dp[layer * NH + h];
    const float* up = hbuf + ((size_t)b * LSEQ + c * TCH) * NH + h;
    __hip_bfloat16* yp = ybf + ((size_t)b * LSEQ + c * TCH) * NH + h;
#pragma unroll 2
    for (int j = 0; j < TCH; j++) {
        float u = up[(size_t)j * NH];
        float a0 = 0.f, a1 = 0.f;
#pragma unroll
        for (int n = 0; n < NN; n++) {
            float nsr = fmaf(er[n], sr[n], fmaf(-ei[n], si[n], u));
            float nsi = fmaf(er[n], si[n], ei[n] * sr[n]);
            sr[n] = nsr; si[n] = nsi;
            if (n & 1) { a1 = fmaf(cr[n], nsr, a1); a1 = fmaf(-ci[n], nsi, a1); }
            else       { a0 = fmaf(cr[n], nsr, a0); a0 = fmaf(-ci[n], nsi, a0); }
        }
        float yv = a0 + a1;
        yv = fmaf(u, dp, yv);
        float g = 0.5f * yv * (1.0f + erff(yv * 0.70710678118f));
        yp[(size_t)j * NH] = __float2bfloat16(g);
    }
}

// ---------------- proj: bf16 MFMA GEMM + GLU + residual + channel-LN ----------------
// block = (b, 64-l tile), 4 waves. Wave w owns o in [64w,64w+64) (a) and +256 (g).
// D = W[512][256] * Y^T ; A-frag: W rows (M,K-contig), B-frag: y rows (N,K-contig).
__global__ void __launch_bounds__(256, 2)
s4w_proj_mfma(const __hip_bfloat16* __restrict__ ybf, float* __restrict__ hbuf,
              const __hip_bfloat16* __restrict__ wbf, const float* __restrict__ ob,
              const float* __restrict__ lnw, const float* __restrict__ lnb, int layer) {
    int b = blockIdx.x;
    int n0 = blockIdx.y * LTILE;
    int t = threadIdx.x;
    int wave = t >> 6, lane = t & 63;
    int lm = lane & 15, kg = lane >> 4;

    __shared__ float glu[LTILE][NH + 1];       // [64][257] f32
    __shared__ float ps[256], pq[256];
    __shared__ float mean_s[LTILE], rstd_s[LTILE];

    f32x4 acc[8][4];
#pragma unroll
    for (int i = 0; i < 8; i++)
#pragma unroll
        for (int j = 0; j < 4; j++) acc[i][j] = (f32x4){0.f, 0.f, 0.f, 0.f};

    const short* wp = (const short*)(wbf) + (size_t)layer * 512 * NH;
    const short* yp = (const short*)(ybf) + ((size_t)b * LSEQ + n0) * NH;

    const short8* aptr[8];
#pragma unroll
    for (int mi = 0; mi < 8; mi++) {
        int o = (mi < 4 ? wave * 64 + mi * 16 : 256 + wave * 64 + (mi - 4) * 16) + lm;
        aptr[mi] = (const short8*)(wp + (size_t)o * NH + kg * 8);
    }
    const short8* bptr[4];
#pragma unroll
    for (int ni = 0; ni < 4; ni++) {
        int l = ni * 16 + lm;
        bptr[ni] = (const short8*)(yp + (size_t)l * NH + kg * 8);
    }

#pragma unroll
    for (int ks = 0; ks < 8; ks++) {          // K = 256 in steps of 32
        short8 bv[4], av[8];
#pragma unroll
        for (int ni = 0; ni < 4; ni++) bv[ni] = bptr[ni][ks * 4];
#pragma unroll
        for (int mi = 0; mi < 8; mi++) av[mi] = aptr[mi][ks * 4];
#pragma unroll
        for (int mi = 0; mi < 8; mi++)
#pragma unroll
            for (int ni = 0; ni < 4; ni++)
                acc[mi][ni] = __builtin_amdgcn_mfma_f32_16x16x32_bf16(av[mi], bv[ni], acc[mi][ni], 0, 0, 0);
    }

    // ---- epilogue: bias + GLU -> LDS ----
    float oba[4][4], obg[4][4];
#pragma unroll
    for (int mi = 0; mi < 4; mi++)
#pragma unroll
        for (int j = 0; j < 4; j++) {
            int o = wave * 64 + mi * 16 + kg * 4 + j;
            oba[mi][j] = ob[layer * 2 * NH + o];
            obg[mi][j] = ob[layer * 2 * NH + NH + o];
        }
#pragma unroll
    for (int mi = 0; mi < 4; mi++)
#pragma unroll
        for (int ni = 0; ni < 4; ni++)
#pragma unroll
            for (int j = 0; j < 4; j++) {
                float a = acc[mi][ni][j] + oba[mi][j];
                float g = acc[mi + 4][ni][j] + obg[mi][j];
                float v = a * (1.0f / (1.0f + expf(-g)));
                int o = wave * 64 + mi * 16 + kg * 4 + j;
                int l = ni * 16 + lm;
                glu[l][o] = v;
            }
    __syncthreads();

    // ---- residual add (coalesced) ----
    const size_t hbase = ((size_t)b * LSEQ + n0) * NH;
    for (int l = 0; l < LTILE; l++)
        glu[l][t] += hbuf[hbase + (size_t)l * NH + t];
    __syncthreads();

    // ---- LN stats ----
    {
        int l = t & 63, seg = t >> 6;
        float s = 0.f, q = 0.f;
#pragma unroll
        for (int i = 0; i < 64; i++) {
            float v = glu[l][seg * 64 + i];
            s += v; q = fmaf(v, v, q);
        }
        ps[t] = s; pq[t] = q;
    }
    __syncthreads();
    if (t < 64) {
        float S = ps[t] + ps[64 + t] + ps[128 + t] + ps[192 + t];
        float Q = pq[t] + pq[64 + t] + pq[128 + t] + pq[192 + t];
        float m = S * (1.0f / NH);
        float v = Q * (1.0f / NH) - m * m;
        mean_s[t] = m; rstd_s[t] = rsqrtf(v + LN_EPS);
    }
    __syncthreads();

    // ---- normalize + write h ----
    float lw = lnw[layer * NH + t], lb = lnb[layer * NH + t];
    for (int l = 0; l < LTILE; l++) {
        float v = (glu[l][t] - mean_s[l]) * rstd_s[l] * lw + lb;
        hbuf[hbase + (size_t)l * NH + t] = v;
    }
}

// ---------------- gather last timestep ----------------
__global__ void s4w_gather(const float* __restrict__ hbuf, float* __restrict__ hl) {
    int idx = blockIdx.x * 256 + threadIdx.x;
    int b = idx / NH, t = idx % NH;
    hl[idx] = hbuf[((size_t)b * LSEQ + (LSEQ - 1)) * NH + t];
}

// ---------------- small MLP layer ----------------
__global__ void s4w_mlp(const float* __restrict__ in, const float* __restrict__ w,
                        const float* __restrict__ bias, float* __restrict__ out,
                        int K, int N, int do_relu) {
    int idx = blockIdx.x * 256 + threadIdx.x;
    if (idx >= NB * N) return;
    int b = idx / N, o = idx % N;
    const float* ip = in + (size_t)b * K;
    const float* wp = w + (size_t)o * K;
    float acc = bias[o];
    for (int k = 0; k < K; k++) acc = fmaf(ip[k], wp[k], acc);
    if (do_relu) acc = fmaxf(acc, 0.f);
    out[idx] = acc;
}

extern "C" void kernel_launch(void* const* d_in, const int* in_sizes, int n_in,
                              void* d_out, int out_size, void* d_ws, size_t ws_size,
                              hipStream_t stream) {
    const float* x          = (const float*)d_in[0];
    const float* enc_w      = (const float*)d_in[1];
    const float* enc_b      = (const float*)d_in[2];
    const float* log_dt     = (const float*)d_in[3];
    const float* C_re       = (const float*)d_in[4];
    const float* C_im       = (const float*)d_in[5];
    const float* log_A_real = (const float*)d_in[6];
    const float* A_imag     = (const float*)d_in[7];
    const float* Dp         = (const float*)d_in[8];
    const float* out_w      = (const float*)d_in[9];
    const float* out_b      = (const float*)d_in[10];
    const float* ln_w       = (const float*)d_in[11];
    const float* ln_b       = (const float*)d_in[12];
    const float* lin1_w     = (const float*)d_in[13];
    const float* lin1_b     = (const float*)d_in[14];
    const float* lin2_w     = (const float*)d_in[15];
    const float* lin2_b     = (const float*)d_in[16];
    const float* lin3_w     = (const float*)d_in[17];
    const float* lin3_b     = (const float*)d_in[18];
    float* outp = (float*)d_out;

    float* ws = (float*)d_ws;
    size_t off = 0;
    float* hbuf   = ws + off; off += (size_t)NB * LSEQ * NH;                       // f32
    __hip_bfloat16* ybf = (__hip_bfloat16*)(ws + off); off += (size_t)NB * LSEQ * NH / 2;  // bf16
    __hip_bfloat16* wbf = (__hip_bfloat16*)(ws + off); off += (size_t)NLAY * 2 * NH * NH / 2;
    float2* states = (float2*)(ws + off); off += (size_t)NB * NCH * NH * NN * 2;
    float* ctr    = ws + off; off += NLAY * NH * NN;
    float* cti    = ws + off; off += NLAY * NH * NN;
    float* er_    = ws + off; off += NLAY * NH * NN;
    float* ei_    = ws + off; off += NLAY * NH * NN;
    float* pr_    = ws + off; off += NLAY * NH * NN;
    float* pi_    = ws + off; off += NLAY * NH * NN;
    float* hl     = ws + off; off += NB * NH;
    float* t1     = ws + off; off += NB * ML1;
    float* t2     = ws + off; off += NB * ML2;

    s4w_coef<<<(NLAY * NH * NN + 255) / 256, 256, 0, stream>>>(
        log_dt, C_re, C_im, log_A_real, A_imag, ctr, cti, er_, ei_, pr_, pi_);

    s4w_wprep<<<(NLAY * 2 * NH * NH) / 256, 256, 0, stream>>>(out_w, wbf);

    s4w_enc<<<dim3(NB * LSEQ / 256, 4), 256, 0, stream>>>(x, enc_w, enc_b, hbuf);

    for (int layer = 0; layer < NLAY; layer++) {
        s4w_convA<<<dim3(NB, NCH), 256, 0, stream>>>(hbuf, er_, ei_, states, layer);
        s4w_scan<<<(NB * NH * NN) / 256, 256, 0, stream>>>(states, pr_, pi_, layer);
        s4w_convC<<<dim3(NB, NCH), 256, 0, stream>>>(hbuf, ybf, states, er_, ei_, ctr, cti, Dp, layer);
        s4w_proj_mfma<<<dim3(NB, LSEQ / LTILE), 256, 0, stream>>>(ybf, hbuf, wbf, out_b, ln_w, ln_b, layer);
    }

    s4w_gather<<<(NB * NH) / 256, 256, 0, stream>>>(hbuf, hl);
    s4w_mlp<<<(NB * ML1 + 255) / 256, 256, 0, stream>>>(hl, lin1_w, lin1_b, t1, NH, ML1, 1);
    s4w_mlp<<<(NB * ML2 + 255) / 256, 256, 0, stream>>>(t1, lin2_w, lin2_b, t2, ML1, ML2, 1);
    s4w_mlp<<<(NB * MOUT + 255) / 256, 256, 0, stream>>>(t2, lin3_w, lin3_b, outp, ML2, MOUT, 0);
}